// Round 1
// baseline (73.409 us; speedup 1.0000x reference)
//
#include <hip/hip_runtime.h>

// Problem: N = 16,777,216 fp32 probabilities + int32 {0,1} targets.
//   count      = #{ p > 0.5 && t == 0 }
//   multiplier = 1 + 0.1*count
//   out        = mean( -(t*log p + (1-t)*log(1-p)) ) * multiplier
// Memory-bound: 128 MiB read -> ~21.3 us floor @ 6.3 TB/s.

#define N_ELEM 16777216
#define N_VEC4 (N_ELEM / 4)

// Workspace layout (d_ws): [0]=double loss_sum, [8]=uint count
__global__ void cl_init(double* __restrict__ g_sum, unsigned int* __restrict__ g_cnt) {
    *g_sum = 0.0;
    *g_cnt = 0u;
}

__global__ __launch_bounds__(256) void cl_reduce(
    const float4* __restrict__ p4,
    const int4*   __restrict__ t4,
    double*       __restrict__ g_sum,
    unsigned int* __restrict__ g_cnt)
{
    float        lsum = 0.0f;
    unsigned int lcnt = 0u;

    const int stride = gridDim.x * blockDim.x;
    for (int i = blockIdx.x * blockDim.x + threadIdx.x; i < N_VEC4; i += stride) {
        const float4 p = p4[i];
        const int4   t = t4[i];

        // BCE element: t==1 -> -log(p); t==0 -> -log(1-p). Select then one log.
        lsum += -__logf(t.x ? p.x : 1.0f - p.x);
        lsum += -__logf(t.y ? p.y : 1.0f - p.y);
        lsum += -__logf(t.z ? p.z : 1.0f - p.z);
        lsum += -__logf(t.w ? p.w : 1.0f - p.w);

        lcnt += (unsigned int)((p.x > 0.5f) & (t.x == 0));
        lcnt += (unsigned int)((p.y > 0.5f) & (t.y == 0));
        lcnt += (unsigned int)((p.z > 0.5f) & (t.z == 0));
        lcnt += (unsigned int)((p.w > 0.5f) & (t.w == 0));
    }

    // 64-lane wave reduction
    #pragma unroll
    for (int off = 32; off > 0; off >>= 1) {
        lsum += __shfl_down(lsum, off);
        lcnt += __shfl_down(lcnt, off);
    }

    // block reduction across 4 waves
    __shared__ float        s_sum[4];
    __shared__ unsigned int s_cnt[4];
    const int wave = threadIdx.x >> 6;
    const int lane = threadIdx.x & 63;
    if (lane == 0) { s_sum[wave] = lsum; s_cnt[wave] = lcnt; }
    __syncthreads();
    if (threadIdx.x == 0) {
        const float        bs = s_sum[0] + s_sum[1] + s_sum[2] + s_sum[3];
        const unsigned int bc = s_cnt[0] + s_cnt[1] + s_cnt[2] + s_cnt[3];
        atomicAdd(g_sum, (double)bs);  // hardware f64 atomic on CDNA
        atomicAdd(g_cnt, bc);
    }
}

__global__ void cl_finalize(const double* __restrict__ g_sum,
                            const unsigned int* __restrict__ g_cnt,
                            float* __restrict__ out)
{
    const double mean = *g_sum * (1.0 / (double)N_ELEM);
    const double mult = 1.0 + 0.1 * (double)(*g_cnt);
    out[0] = (float)(mean * mult);
}

extern "C" void kernel_launch(void* const* d_in, const int* in_sizes, int n_in,
                              void* d_out, int out_size, void* d_ws, size_t ws_size,
                              hipStream_t stream) {
    const float4* p4 = (const float4*)d_in[0];
    const int4*   t4 = (const int4*)d_in[1];
    float*        out = (float*)d_out;

    double*       g_sum = (double*)d_ws;
    unsigned int* g_cnt = (unsigned int*)((char*)d_ws + 8);

    cl_init<<<1, 1, 0, stream>>>(g_sum, g_cnt);

    // 2048 blocks x 256 threads = 524288 threads; 4.19M vec4 -> 8 iters/thread
    cl_reduce<<<2048, 256, 0, stream>>>(p4, t4, g_sum, g_cnt);

    cl_finalize<<<1, 1, 0, stream>>>(g_sum, g_cnt, out);
}

// Round 2
// 66.785 us; speedup vs baseline: 1.0992x; 1.0992x over previous
//
#include <hip/hip_runtime.h>

// N = 16,777,216 fp32 probabilities + int32 {0,1} targets.
//   count      = #{ p > 0.5 && t == 0 }
//   out        = mean( -(t*log p + (1-t)*log(1-p)) ) * (1 + 0.1*count)
// Memory-bound: 128 MiB read -> ~21.3 us floor @ 6.3 TB/s.
//
// R1 lesson: VGPR=12 baseline serialized load->waitcnt->use 8x per wave
// (77 us, latency-bound, BW-independent). Fix: batch 4 load-pairs per
// group so latency is exposed twice per wave, keep VGPR<=64 for 8 waves/SIMD.

#define N_ELEM  16777216
#define N_VEC4  (N_ELEM / 4)      // 4,194,304
#define BLOCKS  2048
#define TPB     256
#define NTHREAD (BLOCKS * TPB)    // 524,288
#define NITER   (N_VEC4 / NTHREAD) // exactly 8
#define GROUPS  2
#define GSIZE   (NITER / GROUPS)  // 4

__global__ void cl_init(double* __restrict__ g_sum, unsigned int* __restrict__ g_cnt) {
    *g_sum = 0.0;
    *g_cnt = 0u;
}

__global__ __launch_bounds__(TPB, 8) void cl_reduce(
    const float4* __restrict__ p4,
    const int4*   __restrict__ t4,
    double*       __restrict__ g_sum,
    unsigned int* __restrict__ g_cnt)
{
    const int tid = blockIdx.x * TPB + threadIdx.x;

    float        lsum = 0.0f;
    unsigned int lcnt = 0u;

    #pragma unroll
    for (int g = 0; g < GROUPS; ++g) {
        float4 p[GSIZE];
        int4   t[GSIZE];
        // Issue all 8 loads back-to-back; compiler stages waitcnts.
        #pragma unroll
        for (int j = 0; j < GSIZE; ++j) {
            const int idx = tid + (g * GSIZE + j) * NTHREAD;
            p[j] = p4[idx];
            t[j] = t4[idx];
        }
        #pragma unroll
        for (int j = 0; j < GSIZE; ++j) {
            lsum += -__logf(t[j].x ? p[j].x : 1.0f - p[j].x);
            lsum += -__logf(t[j].y ? p[j].y : 1.0f - p[j].y);
            lsum += -__logf(t[j].z ? p[j].z : 1.0f - p[j].z);
            lsum += -__logf(t[j].w ? p[j].w : 1.0f - p[j].w);
            lcnt += (unsigned int)((p[j].x > 0.5f) & (t[j].x == 0));
            lcnt += (unsigned int)((p[j].y > 0.5f) & (t[j].y == 0));
            lcnt += (unsigned int)((p[j].z > 0.5f) & (t[j].z == 0));
            lcnt += (unsigned int)((p[j].w > 0.5f) & (t[j].w == 0));
        }
    }

    // 64-lane wave reduction
    #pragma unroll
    for (int off = 32; off > 0; off >>= 1) {
        lsum += __shfl_down(lsum, off);
        lcnt += __shfl_down(lcnt, off);
    }

    // block reduction across 4 waves
    __shared__ float        s_sum[4];
    __shared__ unsigned int s_cnt[4];
    const int wave = threadIdx.x >> 6;
    const int lane = threadIdx.x & 63;
    if (lane == 0) { s_sum[wave] = lsum; s_cnt[wave] = lcnt; }
    __syncthreads();
    if (threadIdx.x == 0) {
        const float        bs = s_sum[0] + s_sum[1] + s_sum[2] + s_sum[3];
        const unsigned int bc = s_cnt[0] + s_cnt[1] + s_cnt[2] + s_cnt[3];
        atomicAdd(g_sum, (double)bs);  // hardware f64 atomic on CDNA
        atomicAdd(g_cnt, bc);
    }
}

__global__ void cl_finalize(const double* __restrict__ g_sum,
                            const unsigned int* __restrict__ g_cnt,
                            float* __restrict__ out)
{
    const double mean = *g_sum * (1.0 / (double)N_ELEM);
    const double mult = 1.0 + 0.1 * (double)(*g_cnt);
    out[0] = (float)(mean * mult);
}

extern "C" void kernel_launch(void* const* d_in, const int* in_sizes, int n_in,
                              void* d_out, int out_size, void* d_ws, size_t ws_size,
                              hipStream_t stream) {
    const float4* p4 = (const float4*)d_in[0];
    const int4*   t4 = (const int4*)d_in[1];
    float*        out = (float*)d_out;

    double*       g_sum = (double*)d_ws;
    unsigned int* g_cnt = (unsigned int*)((char*)d_ws + 8);

    cl_init<<<1, 1, 0, stream>>>(g_sum, g_cnt);
    cl_reduce<<<BLOCKS, TPB, 0, stream>>>(p4, t4, g_sum, g_cnt);
    cl_finalize<<<1, 1, 0, stream>>>(g_sum, g_cnt, out);
}

// Round 3
// 66.140 us; speedup vs baseline: 1.1099x; 1.0097x over previous
//
#include <hip/hip_runtime.h>

// N = 16,777,216 fp32 probabilities + int32 {0,1} targets.
//   count      = #{ p > 0.5 && t == 0 }
//   out        = mean( -(t*log p + (1-t)*log(1-p)) ) * (1 + 0.1*count)
// Memory-bound: 128 MiB read -> ~21.3 us floor @ 6.3 TB/s.
//
// R1: VGPR=12, load->waitcnt(0)->use fully serialized: 77 us, ~1.7 TB/s.
// R2: batched source, but scheduler SANK loads back to uses (VGPR=24): 65 us.
//     Replays (pure L3-resident) identical to HBM pass -> latency-bound,
//     ~2.4 KB in flight per CU. Fix: issue ALL 16 loads, then
//     sched_barrier(0) so the compiler cannot sink them; waitcnt pass then
//     emits staged vmcnt(15..0) drains -> 16 KB in flight per wave.

#define N_ELEM  16777216
#define N_VEC4  (N_ELEM / 4)       // 4,194,304
#define BLOCKS  2048
#define TPB     256
#define NTHREAD (BLOCKS * TPB)     // 524,288
#define NITER   (N_VEC4 / NTHREAD) // exactly 8

__global__ void cl_init(double* __restrict__ g_sum, unsigned int* __restrict__ g_cnt) {
    *g_sum = 0.0;
    *g_cnt = 0u;
}

__global__ __launch_bounds__(TPB, 4) void cl_reduce(
    const float4* __restrict__ p4,
    const int4*   __restrict__ t4,
    double*       __restrict__ g_sum,
    unsigned int* __restrict__ g_cnt)
{
    const int tid = blockIdx.x * TPB + threadIdx.x;

    float4 p[NITER];
    int4   t[NITER];

    // Issue all 16 dwordx4 loads back-to-back (16 KB in flight per wave).
    #pragma unroll
    for (int j = 0; j < NITER; ++j) {
        p[j] = p4[tid + j * NTHREAD];
        t[j] = t4[tid + j * NTHREAD];
    }
    // Hard fence: nothing may be scheduled across this point, so the loads
    // above cannot be sunk down to their uses (the R2 failure mode).
    __builtin_amdgcn_sched_barrier(0);

    float        lsum = 0.0f;
    unsigned int lcnt = 0u;
    #pragma unroll
    for (int j = 0; j < NITER; ++j) {
        // accumulate +log, negate once at the end
        lsum += __logf(t[j].x ? p[j].x : 1.0f - p[j].x);
        lsum += __logf(t[j].y ? p[j].y : 1.0f - p[j].y);
        lsum += __logf(t[j].z ? p[j].z : 1.0f - p[j].z);
        lsum += __logf(t[j].w ? p[j].w : 1.0f - p[j].w);
        lcnt += (unsigned int)((p[j].x > 0.5f) & (t[j].x == 0));
        lcnt += (unsigned int)((p[j].y > 0.5f) & (t[j].y == 0));
        lcnt += (unsigned int)((p[j].z > 0.5f) & (t[j].z == 0));
        lcnt += (unsigned int)((p[j].w > 0.5f) & (t[j].w == 0));
    }
    lsum = -lsum;

    // 64-lane wave reduction
    #pragma unroll
    for (int off = 32; off > 0; off >>= 1) {
        lsum += __shfl_down(lsum, off);
        lcnt += __shfl_down(lcnt, off);
    }

    // block reduction across 4 waves
    __shared__ float        s_sum[4];
    __shared__ unsigned int s_cnt[4];
    const int wave = threadIdx.x >> 6;
    const int lane = threadIdx.x & 63;
    if (lane == 0) { s_sum[wave] = lsum; s_cnt[wave] = lcnt; }
    __syncthreads();
    if (threadIdx.x == 0) {
        const float        bs = s_sum[0] + s_sum[1] + s_sum[2] + s_sum[3];
        const unsigned int bc = s_cnt[0] + s_cnt[1] + s_cnt[2] + s_cnt[3];
        atomicAdd(g_sum, (double)bs);  // hardware f64 atomic on CDNA
        atomicAdd(g_cnt, bc);
    }
}

__global__ void cl_finalize(const double* __restrict__ g_sum,
                            const unsigned int* __restrict__ g_cnt,
                            float* __restrict__ out)
{
    const double mean = *g_sum * (1.0 / (double)N_ELEM);
    const double mult = 1.0 + 0.1 * (double)(*g_cnt);
    out[0] = (float)(mean * mult);
}

extern "C" void kernel_launch(void* const* d_in, const int* in_sizes, int n_in,
                              void* d_out, int out_size, void* d_ws, size_t ws_size,
                              hipStream_t stream) {
    const float4* p4 = (const float4*)d_in[0];
    const int4*   t4 = (const int4*)d_in[1];
    float*        out = (float*)d_out;

    double*       g_sum = (double*)d_ws;
    unsigned int* g_cnt = (unsigned int*)((char*)d_ws + 8);

    cl_init<<<1, 1, 0, stream>>>(g_sum, g_cnt);
    cl_reduce<<<BLOCKS, TPB, 0, stream>>>(p4, t4, g_sum, g_cnt);
    cl_finalize<<<1, 1, 0, stream>>>(g_sum, g_cnt, out);
}

// Round 4
// 30.926 us; speedup vs baseline: 2.3737x; 2.1387x over previous
//
#include <hip/hip_runtime.h>

// N = 16,777,216 fp32 probabilities + int32 {0,1} targets.
//   count      = #{ p > 0.5 && t == 0 }
//   out        = mean( -(t*log p + (1-t)*log(1-p)) ) * (1 + 0.1*count)
// Memory-bound floor: 128 MiB read -> ~21.3 us @ 6.3 TB/s.
//
// R1-R3: 79/65/62 us, all latency-theory fixes ~flat; replays (L3-resident)
// identical to HBM pass; VALUBusy ~13%. Little's-law arithmetic shows per-wave
// ILP was never binding. New theory: atomicAdd(double*) compiles to a CAS
// retry loop (no -munsafe-fp-atomics) -> 2048 blocks contending one address =
// ~50+ us serialized tail. R4: NO atomics. Blocks store disjoint partials to
// d_ws; a second 1-block kernel reduces them. Deterministic, contention-free.

#define N_ELEM  16777216
#define N_VEC4  (N_ELEM / 4)       // 4,194,304
#define BLOCKS  2048
#define TPB     256
#define NTHREAD (BLOCKS * TPB)     // 524,288
#define NITER   (N_VEC4 / NTHREAD) // exactly 8

// d_ws layout: [0 .. BLOCKS)           double  partial loss sums (16 KB)
//              [BLOCKS*8 .. +BLOCKS*4) uint    partial counts    (8 KB)

__global__ __launch_bounds__(TPB, 4) void cl_reduce(
    const float4* __restrict__ p4,
    const int4*   __restrict__ t4,
    double*       __restrict__ psum,
    unsigned int* __restrict__ pcnt)
{
    const int tid = blockIdx.x * TPB + threadIdx.x;

    float4 p[NITER];
    int4   t[NITER];
    #pragma unroll
    for (int j = 0; j < NITER; ++j) {
        p[j] = p4[tid + j * NTHREAD];
        t[j] = t4[tid + j * NTHREAD];
    }
    __builtin_amdgcn_sched_barrier(0);

    float        lsum = 0.0f;
    unsigned int lcnt = 0u;
    #pragma unroll
    for (int j = 0; j < NITER; ++j) {
        lsum += __logf(t[j].x ? p[j].x : 1.0f - p[j].x);
        lsum += __logf(t[j].y ? p[j].y : 1.0f - p[j].y);
        lsum += __logf(t[j].z ? p[j].z : 1.0f - p[j].z);
        lsum += __logf(t[j].w ? p[j].w : 1.0f - p[j].w);
        lcnt += (unsigned int)((p[j].x > 0.5f) & (t[j].x == 0));
        lcnt += (unsigned int)((p[j].y > 0.5f) & (t[j].y == 0));
        lcnt += (unsigned int)((p[j].z > 0.5f) & (t[j].z == 0));
        lcnt += (unsigned int)((p[j].w > 0.5f) & (t[j].w == 0));
    }
    lsum = -lsum;

    // 64-lane wave reduction
    #pragma unroll
    for (int off = 32; off > 0; off >>= 1) {
        lsum += __shfl_down(lsum, off);
        lcnt += __shfl_down(lcnt, off);
    }

    // block reduction across 4 waves -> ONE disjoint store per block, no atomics
    __shared__ float        s_sum[4];
    __shared__ unsigned int s_cnt[4];
    const int wave = threadIdx.x >> 6;
    const int lane = threadIdx.x & 63;
    if (lane == 0) { s_sum[wave] = lsum; s_cnt[wave] = lcnt; }
    __syncthreads();
    if (threadIdx.x == 0) {
        psum[blockIdx.x] = (double)(s_sum[0] + s_sum[1] + s_sum[2] + s_sum[3]);
        pcnt[blockIdx.x] = s_cnt[0] + s_cnt[1] + s_cnt[2] + s_cnt[3];
    }
}

__global__ __launch_bounds__(TPB) void cl_final(
    const double*       __restrict__ psum,
    const unsigned int* __restrict__ pcnt,
    float*              __restrict__ out)
{
    double       s = 0.0;
    unsigned int c = 0u;
    #pragma unroll
    for (int j = 0; j < BLOCKS / TPB; ++j) {   // 8 partials per thread
        s += psum[threadIdx.x + j * TPB];
        c += pcnt[threadIdx.x + j * TPB];
    }
    #pragma unroll
    for (int off = 32; off > 0; off >>= 1) {
        s += __shfl_down(s, off);
        c += __shfl_down(c, off);
    }
    __shared__ double       ss[4];
    __shared__ unsigned int sc[4];
    const int wave = threadIdx.x >> 6;
    const int lane = threadIdx.x & 63;
    if (lane == 0) { ss[wave] = s; sc[wave] = c; }
    __syncthreads();
    if (threadIdx.x == 0) {
        const double       tot = ss[0] + ss[1] + ss[2] + ss[3];
        const unsigned int tc  = sc[0] + sc[1] + sc[2] + sc[3];
        out[0] = (float)((tot * (1.0 / (double)N_ELEM)) * (1.0 + 0.1 * (double)tc));
    }
}

extern "C" void kernel_launch(void* const* d_in, const int* in_sizes, int n_in,
                              void* d_out, int out_size, void* d_ws, size_t ws_size,
                              hipStream_t stream) {
    const float4* p4 = (const float4*)d_in[0];
    const int4*   t4 = (const int4*)d_in[1];
    float*        out = (float*)d_out;

    double*       psum = (double*)d_ws;                          // 2048 * 8 B
    unsigned int* pcnt = (unsigned int*)((char*)d_ws + BLOCKS*8); // 2048 * 4 B

    cl_reduce<<<BLOCKS, TPB, 0, stream>>>(p4, t4, psum, pcnt);
    cl_final<<<1, TPB, 0, stream>>>(psum, pcnt, out);
}